// Round 8
// baseline (237.634 us; speedup 1.0000x reference)
//
#include <hip/hip_runtime.h>
#include <hip/hip_bf16.h>
#include <math.h>

typedef unsigned short u16;
typedef unsigned int u32;
typedef __attribute__((ext_vector_type(8))) short bf16x8;
typedef __attribute__((ext_vector_type(4))) float f32x4;

// B=64, L=256, DIN=768, H=64, E=8, K=2, S=16; BL=16384. All inputs f32, output f32.

__device__ __forceinline__ float bf2f(u16 u) {
    union { u32 i; float f; } x; x.i = ((u32)u) << 16; return x.f;
}
// HW RNE convert — same rounding as manual (i + 0x7fff + lsb)>>16 bit-twiddle.
__device__ __forceinline__ u16 f2bf(float f) {
    union { __hip_bfloat16 h; u16 u; } x;
    x.h = __float2bfloat16(f);
    return x.u;
}
__device__ __forceinline__ u32 pack2(float a, float b) {
    union { __hip_bfloat162 h; u32 u; } x;
    x.h = __float22bfloat162_rn(make_float2(a, b));
    return x.u;
}
__device__ __forceinline__ float wsum(float v) {
    #pragma unroll
    for (int o = 1; o < 64; o <<= 1) v += __shfl_xor(v, o, 64);
    return v;
}
__device__ __forceinline__ float gelu_f(float x) {
    return 0.5f * x * (1.0f + erff(x * 0.70710678118654752440f));
}

// ---------- 1a. partial gating (batched loads) ----------
__global__ __launch_bounds__(256) void k_gate_part(const float* __restrict__ dte,
                                                   const float* __restrict__ w_gate,
                                                   float* __restrict__ partial) {
    __shared__ float dmeanS[64];
    int p = blockIdx.x, tid = threadIdx.x, w = tid >> 6, lane = tid & 63;
    #pragma unroll
    for (int h = 0; h < 2; h++) {
        float4 v[8][3];
        #pragma unroll
        for (int i = 0; i < 8; i++) {
            const float* pr = dte + ((size_t)p * 64 + w * 16 + h * 8 + i) * 768;
            #pragma unroll
            for (int j = 0; j < 3; j++)
                v[i][j] = *(const float4*)(pr + (lane + j * 64) * 4);
        }
        #pragma unroll
        for (int i = 0; i < 8; i++) {
            float s = 0.f;
            #pragma unroll
            for (int j = 0; j < 3; j++)
                s += v[i][j].x + v[i][j].y + v[i][j].z + v[i][j].w;
            s = wsum(s);
            if (lane == 0) dmeanS[w * 16 + h * 8 + i] = s * (1.f / 768.f);
        }
    }
    __syncthreads();
    if (w == 0) {
        float dm = dmeanS[lane];
        int wl = (p & 3) * 64 + lane;
        #pragma unroll
        for (int e = 0; e < 8; e++) {
            float s = wsum(dm * w_gate[wl * 8 + e]);
            if (lane == 0) partial[p * 8 + e] = s;
        }
    }
}

// ---------- 1b. finalize gates + loss ----------
__global__ __launch_bounds__(256) void k_gate_fin(const float* __restrict__ partial,
                                                  const float* __restrict__ b_exp,
                                                  int* __restrict__ topi,
                                                  float* __restrict__ topg,
                                                  float* __restrict__ bias_y,
                                                  float* __restrict__ loss_out) {
    __shared__ float gS[64 * 8];
    __shared__ int i0S[64], i1S[64];
    __shared__ float g0S[64], g1S[64];
    int tid = threadIdx.x;
    if (tid < 64) {
        float lg[8];
        #pragma unroll
        for (int e = 0; e < 8; e++)
            lg[e] = partial[(tid * 4 + 0) * 8 + e] + partial[(tid * 4 + 1) * 8 + e] +
                    partial[(tid * 4 + 2) * 8 + e] + partial[(tid * 4 + 3) * 8 + e];
        int i0 = 0; float v0 = lg[0];
        #pragma unroll
        for (int e = 1; e < 8; e++) if (lg[e] > v0) { v0 = lg[e]; i0 = e; }
        int i1 = -1; float v1 = -1e30f;
        #pragma unroll
        for (int e = 0; e < 8; e++) if (e != i0 && lg[e] > v1) { v1 = lg[e]; i1 = e; }
        if (i1 < 0) i1 = (i0 + 1) & 7;
        float e2 = expf(v1 - v0);
        float g0 = 1.f / (1.f + e2);
        float g1 = e2 / (1.f + e2);
        #pragma unroll
        for (int e = 0; e < 8; e++) gS[tid * 8 + e] = 0.f;
        gS[tid * 8 + i0] = g0;
        gS[tid * 8 + i1] = g1;
        i0S[tid] = i0; i1S[tid] = i1; g0S[tid] = g0; g1S[tid] = g1;
        topi[tid * 2] = i0; topi[tid * 2 + 1] = i1;
        topg[tid * 2] = g0; topg[tid * 2 + 1] = g1;
    }
    __syncthreads();
    for (int idx = tid; idx < 4096; idx += 256) {
        int b = idx >> 6, h = idx & 63;
        bias_y[idx] = g0S[b] * b_exp[i0S[b] * 64 + h] + g1S[b] * b_exp[i1S[b] * 64 + h];
    }
    if (tid < 64) {
        float g[8];
        #pragma unroll
        for (int e = 0; e < 8; e++) g[e] = gS[tid * 8 + e];
        float imp[8], ld[8];
        #pragma unroll
        for (int e = 0; e < 8; e++) {
            imp[e] = wsum(g[e]);
            ld[e]  = wsum(g[e] > 0.f ? 1.f : 0.f);
        }
        if (tid == 0) {
            float l = 0.f;
            {
                float s = 0.f;
                #pragma unroll
                for (int e = 0; e < 8; e++) s += imp[e];
                float mn = s / 8.f, v = 0.f;
                #pragma unroll
                for (int e = 0; e < 8; e++) { float d = imp[e] - mn; v += d * d; }
                l += (v / 7.f) / (mn * mn + 1e-10f);
            }
            {
                float s = 0.f;
                #pragma unroll
                for (int e = 0; e < 8; e++) s += ld[e];
                float mn = s / 8.f, v = 0.f;
                #pragma unroll
                for (int e = 0; e < 8; e++) { float d = ld[e] - mn; v += d * d; }
                l += (v / 7.f) / (mn * mn + 1e-10f);
            }
            loss_out[0] = 0.01f * l;
        }
    }
}

// ---------- 2. MFMA GEMMs, BK=64. FUSED: bid<256 computes BOTH sh (W_sh)
// and y (expert-mix) GEMMs from ONE A-staging; bid>=256: rgb -> out plane.
// Per-accumulator MFMA order unchanged -> bit-identical outputs. ----------
__global__ __launch_bounds__(256) void k_gemm3(const float* __restrict__ dte,
                                               const float* __restrict__ x,
                                               const float* __restrict__ W_sh,
                                               const float* __restrict__ b_sh,
                                               const float* __restrict__ W_exp,
                                               const int* __restrict__ topi,
                                               const float* __restrict__ topg,
                                               const float* __restrict__ bias_y,
                                               const float* __restrict__ W_rgb,
                                               const float* __restrict__ b_rgb,
                                               float* __restrict__ buf_sh,
                                               u16* __restrict__ buf_y,
                                               float* __restrict__ out_rgb) {
    __shared__ __align__(16) u16 As[64 * 72];    // A[r][k], stride 72 u16
    __shared__ __align__(16) u16 Wt0[64 * 72];   // W_sh^T or W_rgb^T [n][k]
    __shared__ __align__(16) u16 Wt1[64 * 72];   // expert mix ^T (fused only)
    int bid = blockIdx.x;
    bool fused = bid < 256;
    int row0 = fused ? bid * 64 : (bid - 256) * 64;
    int b = row0 >> 8;
    int tid = threadIdx.x, wv = tid >> 6, lane = tid & 63;
    int m = lane & 15, quad = lane >> 4;

    const float* A  = fused ? dte : x;
    const float* Wb = fused ? W_sh : W_rgb;
    const float* We0 = W_exp;
    const float* We1 = W_exp;
    float g0 = 0.f, g1 = 0.f;
    if (fused) {
        We0 = W_exp + (size_t)topi[2 * b] * 49152;
        We1 = W_exp + (size_t)topi[2 * b + 1] * 49152;
        g0 = topg[2 * b]; g1 = topg[2 * b + 1];
    }

    // prefetch registers
    float4 pa[2][2];        // A: 2 chunks x 8 floats
    float  pw0[16];         // base weight: 16 consecutive k for one n
    float  pw1[16];         // expert mix (fused only)
    const int a_r  = tid >> 3;            // A chunk 0 row (chunk 1: +32)
    const int a_k8 = (tid & 7) * 8;       // k offset
    const int w_n  = tid & 63;
    const int w_k0 = (tid >> 6) * 16;

    auto loadA = [&](int kc) {
        #pragma unroll
        for (int j = 0; j < 2; j++) {
            const float* src = A + (size_t)(row0 + a_r + j * 32) * 768 + kc * 64 + a_k8;
            pa[j][0] = *(const float4*)(src);
            pa[j][1] = *(const float4*)(src + 4);
        }
    };
    auto loadW = [&](int kc) {
        #pragma unroll
        for (int j = 0; j < 16; j++)
            pw0[j] = Wb[(size_t)(kc * 64 + w_k0 + j) * 64 + w_n];
        if (fused) {
            #pragma unroll
            for (int j = 0; j < 16; j++) {
                size_t off = (size_t)(kc * 64 + w_k0 + j) * 64 + w_n;
                pw1[j] = g0 * We0[off] + g1 * We1[off];
            }
        }
    };
    auto stageLDS = [&]() {
        #pragma unroll
        for (int j = 0; j < 2; j++) {
            uint4 d;
            d.x = pack2(pa[j][0].x, pa[j][0].y);
            d.y = pack2(pa[j][0].z, pa[j][0].w);
            d.z = pack2(pa[j][1].x, pa[j][1].y);
            d.w = pack2(pa[j][1].z, pa[j][1].w);
            *(uint4*)&As[(a_r + j * 32) * 72 + a_k8] = d;
        }
        {
            uint4 d0, d1;
            d0.x = pack2(pw0[0],  pw0[1]);  d0.y = pack2(pw0[2],  pw0[3]);
            d0.z = pack2(pw0[4],  pw0[5]);  d0.w = pack2(pw0[6],  pw0[7]);
            d1.x = pack2(pw0[8],  pw0[9]);  d1.y = pack2(pw0[10], pw0[11]);
            d1.z = pack2(pw0[12], pw0[13]); d1.w = pack2(pw0[14], pw0[15]);
            *(uint4*)&Wt0[w_n * 72 + w_k0]     = d0;
            *(uint4*)&Wt0[w_n * 72 + w_k0 + 8] = d1;
        }
        if (fused) {
            uint4 d0, d1;
            d0.x = pack2(pw1[0],  pw1[1]);  d0.y = pack2(pw1[2],  pw1[3]);
            d0.z = pack2(pw1[4],  pw1[5]);  d0.w = pack2(pw1[6],  pw1[7]);
            d1.x = pack2(pw1[8],  pw1[9]);  d1.y = pack2(pw1[10], pw1[11]);
            d1.z = pack2(pw1[12], pw1[13]); d1.w = pack2(pw1[14], pw1[15]);
            *(uint4*)&Wt1[w_n * 72 + w_k0]     = d0;
            *(uint4*)&Wt1[w_n * 72 + w_k0 + 8] = d1;
        }
    };

    f32x4 z = {0.f, 0.f, 0.f, 0.f};
    f32x4 s0 = z, s1 = z, s2 = z, s3 = z;      // GEMM0 (sh / rgb)
    f32x4 y0 = z, y1 = z, y2 = z, y3 = z;      // GEMM1 (y, fused only)

    loadA(0); loadW(0);
    for (int kc = 0; kc < 12; kc++) {
        __syncthreads();            // previous compute done reading LDS
        stageLDS();
        __syncthreads();            // staged data visible
        if (kc < 11) { loadA(kc + 1); loadW(kc + 1); }   // prefetch overlaps MFMAs
        const int ar = (wv * 16 + m) * 72;
        bf16x8 a0 = *(const bf16x8*)&As[ar + quad * 8];
        bf16x8 a1 = *(const bf16x8*)&As[ar + 32 + quad * 8];
        #pragma unroll
        for (int t = 0; t < 4; t++) {
            const int br = (t * 16 + m) * 72;
            bf16x8 b0 = *(const bf16x8*)&Wt0[br + quad * 8];
            bf16x8 b1 = *(const bf16x8*)&Wt0[br + 32 + quad * 8];
            f32x4* sp = (t == 0) ? &s0 : (t == 1) ? &s1 : (t == 2) ? &s2 : &s3;
            *sp = __builtin_amdgcn_mfma_f32_16x16x32_bf16(a0, b0, *sp, 0, 0, 0);
            *sp = __builtin_amdgcn_mfma_f32_16x16x32_bf16(a1, b1, *sp, 0, 0, 0);
            if (fused) {
                bf16x8 c0 = *(const bf16x8*)&Wt1[br + quad * 8];
                bf16x8 c1 = *(const bf16x8*)&Wt1[br + 32 + quad * 8];
                f32x4* yp = (t == 0) ? &y0 : (t == 1) ? &y1 : (t == 2) ? &y2 : &y3;
                *yp = __builtin_amdgcn_mfma_f32_16x16x32_bf16(a0, c0, *yp, 0, 0, 0);
                *yp = __builtin_amdgcn_mfma_f32_16x16x32_bf16(a1, c1, *yp, 0, 0, 0);
            }
        }
    }

    // epilogue: C[row0 + wv*16 + quad*4 + i][t*16 + m]
    f32x4 accs0[4] = {s0, s1, s2, s3};
    f32x4 accs1[4] = {y0, y1, y2, y3};
    #pragma unroll
    for (int t = 0; t < 4; t++) {
        int col = t * 16 + m;
        if (fused) {
            float bs = b_sh[col];
            float by = bias_y[b * 64 + col];
            #pragma unroll
            for (int i = 0; i < 4; i++) {
                int r = row0 + wv * 16 + quad * 4 + i;
                buf_sh[(size_t)r * 64 + col] = accs0[t][i] + bs;
                buf_y[(size_t)r * 64 + col]  = f2bf(accs1[t][i] + by);
            }
        } else {
            float br = b_rgb[col];
            #pragma unroll
            for (int i = 0; i < 4; i++) {
                int r = row0 + wv * 16 + quad * 4 + i;
                out_rgb[(size_t)r * 64 + col] = accs0[t][i] + br;
            }
        }
    }
}

// ---------- 3. LN + W_px -> t1, t2 (bf16); 32-row tiles, grid 512.
// Wpx staged async global->LDS. GEMM A-operand now read as float4 (4 k-steps
// per load) — halves LDS issue count; same FMA order -> bit-identical. ----------
__global__ __launch_bounds__(256) void k_lnpx(const float* __restrict__ buf_sh,
                                              const float* __restrict__ ln_g,
                                              const float* __restrict__ ln_b,
                                              const float* __restrict__ W_px,
                                              const float* __restrict__ b_px,
                                              u16* __restrict__ t1, u16* __restrict__ t2) {
    __shared__ __align__(16) float T[32 * 68];
    __shared__ __align__(16) float Wpx[8192];
    int r0 = blockIdx.x * 32;
    int tid = threadIdx.x, w = tid >> 6, lane = tid & 63;
    #pragma unroll
    for (int j = 0; j < 8; j++) {
        const float* g = W_px + (size_t)(w * 64 + j * 256) * 4 + lane * 4;
        float* l = Wpx + (w * 64 + j * 256) * 4;
        __builtin_amdgcn_global_load_lds(
            (const __attribute__((address_space(1))) unsigned int*)g,
            (__attribute__((address_space(3))) unsigned int*)l,
            16, 0, 0);
    }
    float lnG = ln_g[lane], lnB = ln_b[lane];
    for (int i = 0; i < 8; i++) {
        int l = w * 8 + i;
        float v = buf_sh[(size_t)(r0 + l) * 64 + lane];
        float mean = wsum(v) * (1.f / 64.f);
        float d = v - mean;
        float var = wsum(d * d) * (1.f / 64.f);
        T[l * 68 + lane] = d * rsqrtf(var + 1e-6f) * lnG + lnB;
    }
    __syncthreads();    // drains vmcnt: Wpx landed
    int rg = tid >> 4, cg = tid & 15;
    float acc1[2][4] = {}, acc2[2][4] = {};
    const float* tr = T + rg * 2 * 68;
    #pragma unroll 2
    for (int k4 = 0; k4 < 64; k4 += 4) {
        float4 av0 = *(const float4*)(tr + k4);
        float4 av1 = *(const float4*)(tr + 68 + k4);
        const float a0s[4] = {av0.x, av0.y, av0.z, av0.w};
        const float a1s[4] = {av1.x, av1.y, av1.z, av1.w};
        #pragma unroll
        for (int q = 0; q < 4; q++) {
            int kk = k4 + q;
            float a0 = a0s[q], a1 = a1s[q];
            float4 w1 = *(const float4*)(Wpx + kk * 128 + cg * 4);
            float4 w2 = *(const float4*)(Wpx + kk * 128 + 64 + cg * 4);
            acc1[0][0] += a0 * w1.x; acc1[0][1] += a0 * w1.y; acc1[0][2] += a0 * w1.z; acc1[0][3] += a0 * w1.w;
            acc1[1][0] += a1 * w1.x; acc1[1][1] += a1 * w1.y; acc1[1][2] += a1 * w1.z; acc1[1][3] += a1 * w1.w;
            acc2[0][0] += a0 * w2.x; acc2[0][1] += a0 * w2.y; acc2[0][2] += a0 * w2.z; acc2[0][3] += a0 * w2.w;
            acc2[1][0] += a1 * w2.x; acc2[1][1] += a1 * w2.y; acc2[1][2] += a1 * w2.z; acc2[1][3] += a1 * w2.w;
        }
    }
    float4 b1 = *(const float4*)(b_px + cg * 4);
    float4 b2 = *(const float4*)(b_px + 64 + cg * 4);
    #pragma unroll
    for (int i = 0; i < 2; i++) {
        int r = r0 + rg * 2 + i;
        u32* d1 = (u32*)(t1 + (size_t)r * 64 + cg * 4);
        d1[0] = pack2(acc1[i][0] + b1.x, acc1[i][1] + b1.y);
        d1[1] = pack2(acc1[i][2] + b1.z, acc1[i][3] + b1.w);
        u32* d2 = (u32*)(t2 + (size_t)r * 64 + cg * 4);
        d2[0] = pack2(acc2[i][0] + b2.x, acc2[i][1] + b2.y);
        d2[1] = pack2(acc2[i][2] + b2.z, acc2[i][3] + b2.w);
    }
}

// ---------- 4. tail; 32-row tiles, grid 512, async weight pipeline.
// GEMM phases now read the A-operand as float4/uint2 (4 k-steps per load):
// LDS ops per k-step 3 -> 1.5, attacking the ds_read->FMA latency chain that
// held VALUBusy at ~25%. Same per-accumulator FMA order -> bit-identical. ----------
__global__ __launch_bounds__(256) void k_tail(const u16* __restrict__ t1,
                                              const u16* __restrict__ t2,
                                              const float* __restrict__ conv_sh,
                                              const float* __restrict__ W_pxx,
                                              const float* __restrict__ b_pxx,
                                              const float* __restrict__ buf_sh,
                                              const u16* __restrict__ buf_y,
                                              const float* __restrict__ W_dte,
                                              const float* __restrict__ b_dte,
                                              const float* __restrict__ W_dteall,
                                              const float* __restrict__ b_dteall,
                                              const float* __restrict__ W_fx,
                                              const float* __restrict__ b_fx,
                                              const float* __restrict__ W_fmod,
                                              const float* __restrict__ b_fmod,
                                              const float* __restrict__ W_fxx,
                                              const float* __restrict__ b_fxx,
                                              float* __restrict__ out) {
    __shared__ __align__(16) float C0[32 * 68];   // conv*t2; reused as P in D2
    __shared__ __align__(16) float GA[32 * 68];   // gelu(out residual)
    __shared__ __align__(16) float SH1[32 * 68];  // pxx GEMM + shortcut
    __shared__ __align__(16) float GM[32 * 68];   // gelu(dte_tok)
    __shared__ __align__(16) u16   Ybh[32 * 72];  // buf_y (bf16, raw copy)
    __shared__ __align__(16) float WL[2][4096];   // ping-pong 16 KB weight tiles
    int r0 = blockIdx.x * 32;
    int tid = threadIdx.x, w = tid >> 6, lane = tid & 63;
    int rg = tid >> 4, cg = tid & 15;

    // async global->LDS stage of one 16 KB matrix: 4 issues/wave, 1 KB each
    auto stage_w = [&](const float* __restrict__ Wsrc, int half) {
        const float* g = Wsrc + w * 1024 + lane * 4;
        float* l = &WL[half][w * 1024];
        #pragma unroll
        for (int j = 0; j < 4; j++) {
            __builtin_amdgcn_global_load_lds(
                (const __attribute__((address_space(1))) unsigned int*)(g + j * 256),
                (__attribute__((address_space(3))) unsigned int*)(l + j * 256),
                16, 0, 0);
        }
    };

    stage_w(W_pxx, 0);                      // pre-A: phase B's weights

    // ---- phase A: issue W_dte; conv, Yb copy, residual+gelu ----
    stage_w(W_dte, 1);
    float4 rsv[2];
    #pragma unroll
    for (int i = 0; i < 2; i++) {
        int r = rg * 2 + i;
        // buf_y raw bf16 copy
        uint2 v = *(const uint2*)(buf_y + (size_t)(r0 + r) * 64 + cg * 4);
        *(uint2*)(&Ybh[r * 72 + cg * 4]) = v;
        // out residual -> registers; gelu -> GA
        rsv[i] = *(const float4*)(out + (size_t)(r0 + r) * 64 + cg * 4);
        GA[r * 68 + cg * 4 + 0] = gelu_f(rsv[i].x);
        GA[r * 68 + cg * 4 + 1] = gelu_f(rsv[i].y);
        GA[r * 68 + cg * 4 + 2] = gelu_f(rsv[i].z);
        GA[r * 68 + cg * 4 + 3] = gelu_f(rsv[i].w);
    }
    {   // depthwise 3x3 conv on t1, * gelu * t2 -> C0 (8 rows/wave)
        float c0 = conv_sh[lane * 9 + 0], c1 = conv_sh[lane * 9 + 1], c2 = conv_sh[lane * 9 + 2];
        float c3 = conv_sh[lane * 9 + 3], c4 = conv_sh[lane * 9 + 4], c5 = conv_sh[lane * 9 + 5];
        float c6 = conv_sh[lane * 9 + 6], c7 = conv_sh[lane * 9 + 7], c8 = conv_sh[lane * 9 + 8];
        #pragma unroll
        for (int i = 0; i < 8; i++) {
            int l = w * 8 + i;
            int gr = r0 + l;
            int pix = gr & 255, ii = pix >> 4, jj = pix & 15;
            const u16* p = t1 + (size_t)gr * 64 + lane;
            float c = c4 * bf2f(p[0]);
            if (ii > 0) {
                c += c1 * bf2f(p[-1024]);
                if (jj > 0)  c += c0 * bf2f(p[-1024 - 64]);
                if (jj < 15) c += c2 * bf2f(p[-1024 + 64]);
            }
            if (jj > 0)  c += c3 * bf2f(p[-64]);
            if (jj < 15) c += c5 * bf2f(p[64]);
            if (ii < 15) {
                c += c7 * bf2f(p[1024]);
                if (jj > 0)  c += c6 * bf2f(p[1024 - 64]);
                if (jj < 15) c += c8 * bf2f(p[1024 + 64]);
            }
            C0[l * 68 + lane] = gelu_f(c) * bf2f(t2[(size_t)gr * 64 + lane]);
        }
    }
    __syncthreads();    // drains vmcnt(0): W_pxx (and W_dte) landed

    // ---- phase B: SH1 = C0 @ W_pxx(WL0) + b_pxx + buf_sh ----
    {
        float acc[2][4] = {};
        const float* ur = C0 + rg * 2 * 68;
        #pragma unroll 4
        for (int k4 = 0; k4 < 64; k4 += 4) {
            float4 av0 = *(const float4*)(ur + k4);
            float4 av1 = *(const float4*)(ur + 68 + k4);
            const float a0s[4] = {av0.x, av0.y, av0.z, av0.w};
            const float a1s[4] = {av1.x, av1.y, av1.z, av1.w};
            #pragma unroll
            for (int q = 0; q < 4; q++) {
                float a0 = a0s[q], a1 = a1s[q];
                float4 wv = *(const float4*)(&WL[0][(k4 + q) * 64 + cg * 4]);
                acc[0][0] += a0 * wv.x; acc[0][1] += a0 * wv.y; acc[0][2] += a0 * wv.z; acc[0][3] += a0 * wv.w;
                acc[1][0] += a1 * wv.x; acc[1][1] += a1 * wv.y; acc[1][2] += a1 * wv.z; acc[1][3] += a1 * wv.w;
            }
        }
        float4 bp = *(const float4*)(b_pxx + cg * 4);
        #pragma unroll
        for (int i = 0; i < 2; i++) {
            int r = rg * 2 + i;
            float4 shv = *(const float4*)(buf_sh + (size_t)(r0 + r) * 64 + cg * 4);
            *(float4*)(SH1 + r * 68 + cg * 4) =
                make_float4(acc[i][0] + bp.x + shv.x, acc[i][1] + bp.y + shv.y,
                            acc[i][2] + bp.z + shv.z, acc[i][3] + bp.w + shv.w);
        }
    }
    __syncthreads();

    // ---- phase C1: issue W_dteall->WL0; accC = Yb @ W_dte(WL1) ----
    float accC[2][4] = {};
    stage_w(W_dteall, 0);
    {
        const u16* yr = Ybh + rg * 2 * 72;
        #pragma unroll 4
        for (int k4 = 0; k4 < 64; k4 += 4) {
            uint2 yv0 = *(const uint2*)(yr + k4);
            uint2 yv1 = *(const uint2*)(yr + 72 + k4);
            const float y0s[4] = {bf2f((u16)(yv0.x & 0xffffu)), bf2f((u16)(yv0.x >> 16)),
                                  bf2f((u16)(yv0.y & 0xffffu)), bf2f((u16)(yv0.y >> 16))};
            const float y1s[4] = {bf2f((u16)(yv1.x & 0xffffu)), bf2f((u16)(yv1.x >> 16)),
                                  bf2f((u16)(yv1.y & 0xffffu)), bf2f((u16)(yv1.y >> 16))};
            #pragma unroll
            for (int q = 0; q < 4; q++) {
                float y0 = y0s[q], y1 = y1s[q];
                float4 wv = *(const float4*)(&WL[1][(k4 + q) * 64 + cg * 4]);
                accC[0][0] += y0 * wv.x; accC[0][1] += y0 * wv.y; accC[0][2] += y0 * wv.z; accC[0][3] += y0 * wv.w;
                accC[1][0] += y1 * wv.x; accC[1][1] += y1 * wv.y; accC[1][2] += y1 * wv.z; accC[1][3] += y1 * wv.w;
            }
        }
    }
    __syncthreads();

    // ---- phase C2: issue W_fx->WL1; accC += SH1 @ W_dteall(WL0); GM = gelu ----
    stage_w(W_fx, 1);
    {
        const float* sr = SH1 + rg * 2 * 68;
        #pragma unroll 4
        for (int k4 = 0; k4 < 64; k4 += 4) {
            float4 av0 = *(const float4*)(sr + k4);
            float4 av1 = *(const float4*)(sr + 68 + k4);
            const float s0s[4] = {av0.x, av0.y, av0.z, av0.w};
            const float s1s[4] = {av1.x, av1.y, av1.z, av1.w};
            #pragma unroll
            for (int q = 0; q < 4; q++) {
                float s0 = s0s[q], s1 = s1s[q];
                float4 wv = *(const float4*)(&WL[0][(k4 + q) * 64 + cg * 4]);
                accC[0][0] += s0 * wv.x; accC[0][1] += s0 * wv.y; accC[0][2] += s0 * wv.z; accC[0][3] += s0 * wv.w;
                accC[1][0] += s1 * wv.x; accC[1][1] += s1 * wv.y; accC[1][2] += s1 * wv.z; accC[1][3] += s1 * wv.w;
            }
        }
        float4 bd1 = *(const float4*)(b_dte + cg * 4);
        float4 bd2 = *(const float4*)(b_dteall + cg * 4);
        #pragma unroll
        for (int i = 0; i < 2; i++) {
            int r = rg * 2 + i;
            *(float4*)(GM + r * 68 + cg * 4) =
                make_float4(gelu_f(accC[i][0] + bd1.x + bd2.x), gelu_f(accC[i][1] + bd1.y + bd2.y),
                            gelu_f(accC[i][2] + bd1.z + bd2.z), gelu_f(accC[i][3] + bd1.w + bd2.w));
        }
    }
    __syncthreads();

    // ---- phase D1: issue W_fmod->WL0; accA = GA @ W_fx(WL1) ----
    float accA[2][4] = {};
    stage_w(W_fmod, 0);
    {
        const float* ga = GA + rg * 2 * 68;
        #pragma unroll 4
        for (int k4 = 0; k4 < 64; k4 += 4) {
            float4 av0 = *(const float4*)(ga + k4);
            float4 av1 = *(const float4*)(ga + 68 + k4);
            const float a0s[4] = {av0.x, av0.y, av0.z, av0.w};
            const float a1s[4] = {av1.x, av1.y, av1.z, av1.w};
            #pragma unroll
            for (int q = 0; q < 4; q++) {
                float a0 = a0s[q], a1 = a1s[q];
                float4 wv = *(const float4*)(&WL[1][(k4 + q) * 64 + cg * 4]);
                accA[0][0] += a0 * wv.x; accA[0][1] += a0 * wv.y; accA[0][2] += a0 * wv.z; accA[0][3] += a0 * wv.w;
                accA[1][0] += a1 * wv.x; accA[1][1] += a1 * wv.y; accA[1][2] += a1 * wv.z; accA[1][3] += a1 * wv.w;
            }
        }
    }
    __syncthreads();

    // ---- phase D2: issue W_fxx->WL1; accM = GM @ W_fmod(WL0);
    //      P(C0) = gelu(accM+bm) * (accA+bx) ----
    stage_w(W_fxx, 1);
    {
        float accM[2][4] = {};
        const float* gm = GM + rg * 2 * 68;
        #pragma unroll 4
        for (int k4 = 0; k4 < 64; k4 += 4) {
            float4 av0 = *(const float4*)(gm + k4);
            float4 av1 = *(const float4*)(gm + 68 + k4);
            const float m0s[4] = {av0.x, av0.y, av0.z, av0.w};
            const float m1s[4] = {av1.x, av1.y, av1.z, av1.w};
            #pragma unroll
            for (int q = 0; q < 4; q++) {
                float m0 = m0s[q], m1 = m1s[q];
                float4 wv = *(const float4*)(&WL[0][(k4 + q) * 64 + cg * 4]);
                accM[0][0] += m0 * wv.x; accM[0][1] += m0 * wv.y; accM[0][2] += m0 * wv.z; accM[0][3] += m0 * wv.w;
                accM[1][0] += m1 * wv.x; accM[1][1] += m1 * wv.y; accM[1][2] += m1 * wv.z; accM[1][3] += m1 * wv.w;
            }
        }
        float4 bx = *(const float4*)(b_fx + cg * 4);
        float4 bm = *(const float4*)(b_fmod + cg * 4);
        #pragma unroll
        for (int i = 0; i < 2; i++) {
            int r = rg * 2 + i;
            float a0 = accA[i][0] + bx.x, a1 = accA[i][1] + bx.y, a2 = accA[i][2] + bx.z, a3 = accA[i][3] + bx.w;
            float m0 = accM[i][0] + bm.x, m1 = accM[i][1] + bm.y, m2 = accM[i][2] + bm.z, m3 = accM[i][3] + bm.w;
            *(float4*)(C0 + r * 68 + cg * 4) =
                make_float4(gelu_f(m0) * a0, gelu_f(m1) * a1, gelu_f(m2) * a2, gelu_f(m3) * a3);
        }
    }
    __syncthreads();

    // ---- phase E: out = P(C0) @ W_fxx(WL1) + b_fxx + rsv ----
    {
        float acc[2][4] = {};
        const float* pr = C0 + rg * 2 * 68;
        #pragma unroll 4
        for (int k4 = 0; k4 < 64; k4 += 4) {
            float4 av0 = *(const float4*)(pr + k4);
            float4 av1 = *(const float4*)(pr + 68 + k4);
            const float p0s[4] = {av0.x, av0.y, av0.z, av0.w};
            const float p1s[4] = {av1.x, av1.y, av1.z, av1.w};
            #pragma unroll
            for (int q = 0; q < 4; q++) {
                float p0 = p0s[q], p1 = p1s[q];
                float4 wv = *(const float4*)(&WL[1][(k4 + q) * 64 + cg * 4]);
                acc[0][0] += p0 * wv.x; acc[0][1] += p0 * wv.y; acc[0][2] += p0 * wv.z; acc[0][3] += p0 * wv.w;
                acc[1][0] += p1 * wv.x; acc[1][1] += p1 * wv.y; acc[1][2] += p1 * wv.z; acc[1][3] += p1 * wv.w;
            }
        }
        float4 bo = *(const float4*)(b_fxx + cg * 4);
        #pragma unroll
        for (int i = 0; i < 2; i++) {
            int r = rg * 2 + i;
            *(float4*)(out + (size_t)(r0 + r) * 64 + cg * 4) =
                make_float4(acc[i][0] + bo.x + rsv[i].x, acc[i][1] + bo.y + rsv[i].y,
                            acc[i][2] + bo.z + rsv[i].z, acc[i][3] + bo.w + rsv[i].w);
        }
    }
}

extern "C" void kernel_launch(void* const* d_in, const int* in_sizes, int n_in,
                              void* d_out, int out_size, void* d_ws, size_t ws_size,
                              hipStream_t stream) {
    const float* x       = (const float*)d_in[0];
    const float* dte     = (const float*)d_in[1];
    const float* w_gate  = (const float*)d_in[2];
    const float* W_exp   = (const float*)d_in[3];
    const float* b_exp   = (const float*)d_in[4];
    const float* W_sh    = (const float*)d_in[5];
    const float* b_sh    = (const float*)d_in[6];
    const float* ln_g    = (const float*)d_in[7];
    const float* ln_b    = (const float*)d_in[8];
    const float* W_px    = (const float*)d_in[9];
    const float* b_px    = (const float*)d_in[10];
    const float* conv_sh = (const float*)d_in[11];
    const float* W_pxx   = (const float*)d_in[12];
    const float* b_pxx   = (const float*)d_in[13];
    const float* W_dte   = (const float*)d_in[14];
    const float* b_dte   = (const float*)d_in[15];
    const float* W_dteall= (const float*)d_in[16];
    const float* b_dteall= (const float*)d_in[17];
    const float* W_rgb   = (const float*)d_in[18];
    const float* b_rgb   = (const float*)d_in[19];
    const float* W_fx    = (const float*)d_in[20];
    const float* b_fx    = (const float*)d_in[21];
    const float* W_fmod  = (const float*)d_in[22];
    const float* b_fmod  = (const float*)d_in[23];
    const float* W_fxx   = (const float*)d_in[24];
    const float* b_fxx   = (const float*)d_in[25];

    float* out = (float*)d_out;     // [0,1048576) plane + loss at [1048576]

    float* wsf    = (float*)d_ws;
    float* partial= wsf;                         // 2048
    int*   topi   = (int*)(wsf + 2048);          // 128
    float* topg   = wsf + 2176;                  // 128
    float* bias_y = wsf + 2304;                  // 4096
    float* buf_sh = wsf + 8192;                  // 1048576 f32
    u16*   buf_y  = (u16*)(wsf + 8192 + 1048576);
    u16*   t1     = (u16*)(wsf + 8192 + 1048576 + 524288);
    u16*   t2     = (u16*)(wsf + 8192 + 1048576 + 524288*2);

    hipLaunchKernelGGL(k_gate_part, dim3(256), dim3(256), 0, stream, dte, w_gate, partial);
    hipLaunchKernelGGL(k_gate_fin, dim3(1), dim3(256), 0, stream,
                       partial, b_exp, topi, topg, bias_y, out + 1048576);
    hipLaunchKernelGGL(k_gemm3, dim3(512), dim3(256), 0, stream,
                       dte, x, W_sh, b_sh, W_exp, topi, topg, bias_y, W_rgb, b_rgb,
                       buf_sh, buf_y, out);
    hipLaunchKernelGGL(k_lnpx, dim3(512), dim3(256), 0, stream,
                       buf_sh, ln_g, ln_b, W_px, b_px, t1, t2);
    hipLaunchKernelGGL(k_tail, dim3(512), dim3(256), 0, stream,
                       t1, t2, conv_sh, W_pxx, b_pxx, buf_sh, buf_y,
                       W_dte, b_dte, W_dteall, b_dteall,
                       W_fx, b_fx, W_fmod, b_fmod, W_fxx, b_fxx, out);

    (void)in_sizes; (void)n_in; (void)out_size; (void)ws_size;
}